// Round 2
// baseline (106.641 us; speedup 1.0000x reference)
//
#include <hip/hip_runtime.h>
#include <math.h>

// QuanvolutionHybrid: conv2x2/s2 -> reshape(196,4) -> L2 norm ->
// all-pairs cos^2 >= 0.8 -> degree -> concat(784+196) -> linear(10) -> log_softmax
// R20: one image per block (8192 blocks). R19's occupancy bump (256,7) was a
//      null result -> residency of identical-phase waves isn't the limit; the
//      7-barrier phase chain is. Halve the per-block critical path instead:
//      every phase now processes 1 image, LDS 22.5KB -> 14.2KB, 8 blocks/CU
//      (wave-slot capped) with 2x block-level phase diversity to overlap the
//      LDS-heavy and MFMA-heavy segments across blocks.
//      Phase 4a: 12 jobs = 6 col-stripes x 2 row-halves, 3 jobs/wave,
//      3 MFMAs each (critical path 9 tiles vs 18). Row-half partials combine
//      in 4c (s_deg0 + s_deg1 + s_cred). Boundary rows 192..195: one row per
//      wave, single image (R6-proven ballot/popcount tail). zacc pinned (R16).
//      Counting stays plain C on MFMA results (R15 lesson).

#define NP 196
#define FEAT 980
#define COS_TH 0.894427190999915878f   // sqrt(0.8)

typedef short v4s  __attribute__((ext_vector_type(4)));
typedef short v8s  __attribute__((ext_vector_type(8)));
typedef float v16f __attribute__((ext_vector_type(16)));

static __device__ __forceinline__ float bf2f(short s) {
    return __uint_as_float(((uint32_t)(uint16_t)s) << 16);
}

__global__ __launch_bounds__(256, 8) void quanv_kernel(
    const float* __restrict__ x,        // (8192, 784)
    const float* __restrict__ conv_w,   // (4,1,2,2) = 16
    const float* __restrict__ conv_b,   // (4,)
    const float* __restrict__ lin_w,    // (10, 980)
    const float* __restrict__ lin_b,    // (10,)
    float* __restrict__ out)            // (8192, 10)
{
    // No overlays this round: total 14.2 KB -> 8 blocks/CU fits easily (113KB).
    __shared__ __align__(16) float s_x[784];
    __shared__ __align__(16) short s_P[256][8];   // bf16 row: h0..h3,l0..l3; rows>=196 zero
    __shared__ __align__(16) float s_feats[FEAT];
    __shared__ __align__(16) int   s_deg0[192];   // row-half 0 partial col-counts
    __shared__ __align__(16) int   s_deg1[192];   // row-half 1 partial col-counts
    __shared__ __align__(16) int   s_cred[196];   // boundary-row credits
    __shared__ __align__(16) float s_part[250];
    __shared__ __align__(16) float s_logits[10];

    const int b = blockIdx.x;            // 8192 blocks, 1 image each
    const int t = threadIdx.x;
    const int w = t >> 6, l = t & 63;

    // ---- Phase 1: stage the image ----
    if (t < NP)
        ((float4*)s_x)[t] = ((const float4*)(x + (size_t)b * 784))[t];
    __syncthreads();

    // ---- Phase 2: conv -> s_feats[0..784) channel-major ----
    if (t < NP) {
        int h = t / 14, ww = t - 14 * (t / 14);
        const float* r0 = s_x + (2 * h) * 28 + 2 * ww;
        float x00 = r0[0], x01 = r0[1], x10 = r0[28], x11 = r0[29];
        #pragma unroll
        for (int c = 0; c < 4; ++c) {
            float f = conv_b[c]
                    + conv_w[c * 4 + 0] * x00 + conv_w[c * 4 + 1] * x01
                    + conv_w[c * 4 + 2] * x10 + conv_w[c * 4 + 3] * x11;
            s_feats[c * NP + t] = f;
        }
    }
    __syncthreads();

    // ---- Phase 3: normalize + exact bf16 hi/lo split -> s_P; zero pads + cred ----
    {
        v8s pk = {0, 0, 0, 0, 0, 0, 0, 0};
        if (t < NP) {
            float4 v = ((const float4*)s_feats)[t];
            float n = sqrtf(v.x * v.x + v.y * v.y + v.z * v.z + v.w * v.w);
            float inv = 1.0f / (n + 1e-12f);
            float e[4] = { v.x * inv, v.y * inv, v.z * inv, v.w * inv };
            #pragma unroll
            for (int k = 0; k < 4; ++k) {
                uint32_t bx = __float_as_uint(e[k]);
                uint32_t rh = bx + 0x7FFFu + ((bx >> 16) & 1u);   // RNE bf16
                uint32_t hk = rh >> 16;
                float hif = __uint_as_float(hk << 16);
                float res = e[k] - hif;                            // exact
                uint32_t br = __float_as_uint(res);
                uint32_t rl = br + 0x7FFFu + ((br >> 16) & 1u);
                pk[k]     = (short)hk;
                pk[4 + k] = (short)(rl >> 16);
            }
        }
        *(v8s*)&s_P[t][0] = pk;
        if (t < NP) s_cred[t] = 0;
    }
    __syncthreads();

    // Persistent zero C-operand: built once, pinned.
    v16f zacc = {0.f,0.f,0.f,0.f,0.f,0.f,0.f,0.f,
                 0.f,0.f,0.f,0.f,0.f,0.f,0.f,0.f};
    asm("" : "+v"(zacc));

    const int ln = l & 31, half = l >> 5;

    // ---- Phase 4a: MFMA core, rows/cols 0..191.
    //      12 jobs = (stripe j 0..5) x (rowhalf h 0..1); 3 jobs/wave, 3 tiles each.
    #pragma unroll
    for (int jj = 0; jj < 3; ++jj) {
        const int job = w + 4 * jj;          // 0..11, wave-uniform
        const int j = job >> 1;              // col-stripe 0..5
        const int h = job & 1;               // row-half 0..1
        const short* Pbase = &s_P[0][0];

        v4s bh = *(const v4s*)(Pbase + (32 * j + ln) * 8 + 4 * half);
        v8s B = __builtin_shufflevector(bh, bh, 0, 1, 2, 3, 0, 1, 2, 3);

        unsigned c0 = 0u, c1 = 0u;
        #pragma unroll
        for (int ii = 0; ii < 3; ++ii) {
            const int i = 3 * h + ii;        // row-tile 0..5
            v8s A = *(const v8s*)(Pbase + (32 * i + ln) * 8);
            v16f acc = __builtin_amdgcn_mfma_f32_32x32x16_bf16(A, B, zacc, 0, 0, 0);
            #pragma unroll
            for (int e = 0; e < 16; e += 2) {
                c0 += (fabsf(acc[e])     >= COS_TH) ? 1u : 0u;
                c1 += (fabsf(acc[e + 1]) >= COS_TH) ? 1u : 0u;
            }
        }
        unsigned cnt = c0 + c1;
        cnt += __shfl_down(cnt, 32, 64);   // merge the two row-halves of the tile
        if (l < 32) {
            int* dst = h ? s_deg1 : s_deg0;
            dst[32 * j + l] = (int)cnt;
        }
    }

    // ---- Phase 4b: boundary rows 192..195 (wave w owns row 192+w).
    // fp32 dots from reconstructed h+l (consistent with split-path values).
    {
        const int r = 192 + w;
        const short* pr = &s_P[r][0];
        float pe0 = bf2f(pr[0]) + bf2f(pr[4]);
        float pe1 = bf2f(pr[1]) + bf2f(pr[5]);
        float pe2 = bf2f(pr[2]) + bf2f(pr[6]);
        float pe3 = bf2f(pr[3]) + bf2f(pr[7]);
        unsigned total = 0u;
        #pragma unroll
        for (int k = 0; k < 4; ++k) {
            int q = 64 * k + l;              // rows >=196 are zero -> miss
            const short* qr = &s_P[q][0];
            float d =          pe0 * (bf2f(qr[0]) + bf2f(qr[4]));
            d = fmaf(pe1, bf2f(qr[1]) + bf2f(qr[5]), d);
            d = fmaf(pe2, bf2f(qr[2]) + bf2f(qr[6]), d);
            d = fmaf(pe3, bf2f(qr[3]) + bf2f(qr[7]), d);
            bool hit = fabsf(d) >= COS_TH;
            unsigned long long m = __ballot(hit);
            total += (unsigned)__popcll(m);
            if (hit && q < 192)
                atomicAdd(&s_cred[q], 1);    // sparse (~4%)
        }
        if (l == 0)
            s_feats[784 + r] = (float)(int)total - 1.0f;  // self-edge
    }
    __syncthreads();

    // ---- Phase 4c: combine half-counts + boundary credits -> deg features ----
    if (t < 192)
        s_feats[784 + t] = (float)(s_deg0[t] + s_deg1[t] + s_cred[t]) - 1.0f;
    __syncthreads();

    // ---- Phase 5: linear ----
    if (t < 250) {
        int k = t / 25, c = t - 25 * (t / 25);
        const float4* wrow = (const float4*)(lin_w + k * FEAT);
        const float4* fp = (const float4*)s_feats;
        float a0 = 0.0f;
        for (int i = c; i < 245; i += 25) {
            float4 wv = wrow[i];
            float4 f0 = fp[i];
            a0 = fmaf(f0.x, wv.x, a0);
            a0 = fmaf(f0.y, wv.y, a0);
            a0 = fmaf(f0.z, wv.z, a0);
            a0 = fmaf(f0.w, wv.w, a0);
        }
        s_part[t] = a0;
    }
    __syncthreads();

    if (t < 10) {
        float s = lin_b[t];
        #pragma unroll
        for (int i = 0; i < 25; ++i) s += s_part[t * 25 + i];
        s_logits[t] = s;
    }
    __syncthreads();

    // ---- Phase 6: log_softmax ----
    if (t < 10) {
        float m = -INFINITY;
        #pragma unroll
        for (int j2 = 0; j2 < 10; ++j2) m = fmaxf(m, s_logits[j2]);
        float s = 0.0f;
        #pragma unroll
        for (int j2 = 0; j2 < 10; ++j2) s += expf(s_logits[j2] - m);
        out[(size_t)b * 10 + t] = s_logits[t] - m - logf(s);
    }
}

extern "C" void kernel_launch(void* const* d_in, const int* in_sizes, int n_in,
                              void* d_out, int out_size, void* d_ws, size_t ws_size,
                              hipStream_t stream) {
    const float* x      = (const float*)d_in[0];
    const float* conv_w = (const float*)d_in[1];
    const float* conv_b = (const float*)d_in[2];
    const float* lin_w  = (const float*)d_in[3];
    const float* lin_b  = (const float*)d_in[4];
    float* out = (float*)d_out;
    quanv_kernel<<<dim3(8192), dim3(256), 0, stream>>>(x, conv_w, conv_b, lin_w, lin_b, out);
}

// Round 4
// 104.969 us; speedup vs baseline: 1.0159x; 1.0159x over previous
//
#include <hip/hip_runtime.h>
#include <math.h>

// QuanvolutionHybrid: conv2x2/s2 -> reshape(196,4) -> L2 norm ->
// all-pairs cos^2 >= 0.8 -> degree -> concat(784+196) -> linear(10) -> log_softmax
// R22: R21 minus the fatal fusion. R21 normalized the per-pixel CHANNEL vector,
//      but the reference's patch vectors are flat.reshape(196,4) of the
//      channel-major flatten -- consecutive quadruples straddling channels.
//      That regroup is a cross-wave permutation -> must round-trip through LDS:
//      conv -> s_feats (channel-major) -> barrier -> float4 read = patch vector.
//      Kept from R21: s_x eliminated (conv reads global directly), one less
//      barrier than R20, __frsqrt_rn (<=0.5ulp), 4a A-fragment hoist (h=w&1 is
//      wave-constant -> 3 ds_read_b128/wave not 9), 4b ds_read_b128 + u32
//      shift/mask bf16 unpack. Counting stays plain C on MFMA results (R15);
//      zacc pinned (R16). LDS ~11.4KB; 8 blocks/CU (wave-slot capped).

#define NP 196
#define FEAT 980
#define COS_TH 0.894427190999915878f   // sqrt(0.8)

typedef short v4s  __attribute__((ext_vector_type(4)));
typedef short v8s  __attribute__((ext_vector_type(8)));
typedef float v16f __attribute__((ext_vector_type(16)));
typedef unsigned int u32;

static __device__ __forceinline__ float bfhi(u32 u) {   // low short -> f32
    return __uint_as_float(u << 16);
}
static __device__ __forceinline__ float bflo(u32 u) {   // high short -> f32
    return __uint_as_float(u & 0xFFFF0000u);
}

__global__ __launch_bounds__(256, 8) void quanv_kernel(
    const float* __restrict__ x,        // (8192, 784)
    const float* __restrict__ conv_w,   // (4,1,2,2) = 16
    const float* __restrict__ conv_b,   // (4,)
    const float* __restrict__ lin_w,    // (10, 980)
    const float* __restrict__ lin_b,    // (10,)
    float* __restrict__ out)            // (8192, 10)
{
    __shared__ __align__(16) short s_P[256][8];   // bf16 row: h0..h3,l0..l3; rows>=196 zero
    __shared__ __align__(16) float s_feats[FEAT];
    __shared__ __align__(16) int   s_deg0[192];   // row-half 0 partial col-counts
    __shared__ __align__(16) int   s_deg1[192];   // row-half 1 partial col-counts
    __shared__ __align__(16) int   s_cred[196];   // boundary-row credits
    __shared__ __align__(16) float s_part[250];
    __shared__ __align__(16) float s_logits[10];

    const int b = blockIdx.x;            // 8192 blocks, 1 image each
    const int t = threadIdx.x;
    const int w = t >> 6, l = t & 63;

    // ---- Phase 1: load x -> conv in regs -> s_feats (channel-major) ----
    if (t < NP) {
        const int h = t / 14, ww = t - 14 * (t / 14);
        const float* xb = x + (size_t)b * 784 + (2 * h) * 28 + 2 * ww;
        float2 r0 = *(const float2*)(xb);
        float2 r1 = *(const float2*)(xb + 28);
        #pragma unroll
        for (int c = 0; c < 4; ++c) {
            float f = conv_b[c]
                    + conv_w[c * 4 + 0] * r0.x + conv_w[c * 4 + 1] * r0.y
                    + conv_w[c * 4 + 2] * r1.x + conv_w[c * 4 + 3] * r1.y;
            s_feats[c * NP + t] = f;
        }
        s_cred[t] = 0;
    }
    __syncthreads();

    // ---- Phase 2: regrouped float4 read (= reference patch vector) ->
    //      normalize -> exact bf16 hi/lo split -> s_P ----
    {
        v8s pk = {0, 0, 0, 0, 0, 0, 0, 0};
        if (t < NP) {
            float4 v = ((const float4*)s_feats)[t];
            float ss = v.x * v.x + v.y * v.y + v.z * v.z + v.w * v.w;
            float inv = __frsqrt_rn(fmaxf(ss, 1e-24f));
            float e[4] = { v.x * inv, v.y * inv, v.z * inv, v.w * inv };
            #pragma unroll
            for (int k = 0; k < 4; ++k) {
                uint32_t bx = __float_as_uint(e[k]);
                uint32_t rh = bx + 0x7FFFu + ((bx >> 16) & 1u);   // RNE bf16
                uint32_t hk = rh >> 16;
                float hif = __uint_as_float(hk << 16);
                float res = e[k] - hif;                            // exact
                uint32_t br = __float_as_uint(res);
                uint32_t rl = br + 0x7FFFu + ((br >> 16) & 1u);
                pk[k]     = (short)hk;
                pk[4 + k] = (short)(rl >> 16);
            }
        }
        *(v8s*)&s_P[t][0] = pk;            // rows >= 196 get zeros
    }
    __syncthreads();

    // Persistent zero C-operand: built once, pinned.
    v16f zacc = {0.f,0.f,0.f,0.f,0.f,0.f,0.f,0.f,
                 0.f,0.f,0.f,0.f,0.f,0.f,0.f,0.f};
    asm("" : "+v"(zacc));

    const int ln = l & 31, half = l >> 5;

    // ---- Phase 4a: MFMA core, rows/cols 0..191.
    //      12 jobs = (stripe j 0..5) x (rowhalf h 0..1), h = w&1 is wave-constant
    //      -> A fragments (rows 96h..96h+95) hoisted, loaded once per wave.
    {
        const int h = w & 1;
        const int jbase = w >> 1;
        const short* Pbase = &s_P[0][0];

        const v8s A0 = *(const v8s*)(Pbase + (32 * (3 * h + 0) + ln) * 8);
        const v8s A1 = *(const v8s*)(Pbase + (32 * (3 * h + 1) + ln) * 8);
        const v8s A2 = *(const v8s*)(Pbase + (32 * (3 * h + 2) + ln) * 8);

        #pragma unroll
        for (int jj = 0; jj < 3; ++jj) {
            const int j = jbase + 2 * jj;    // col-stripe 0..5, wave-uniform
            v4s bh = *(const v4s*)(Pbase + (32 * j + ln) * 8 + 4 * half);
            v8s B = __builtin_shufflevector(bh, bh, 0, 1, 2, 3, 0, 1, 2, 3);

            unsigned c0 = 0u, c1 = 0u;
            #pragma unroll
            for (int ii = 0; ii < 3; ++ii) {
                const v8s A = (ii == 0) ? A0 : (ii == 1) ? A1 : A2;
                v16f acc = __builtin_amdgcn_mfma_f32_32x32x16_bf16(A, B, zacc, 0, 0, 0);
                #pragma unroll
                for (int e = 0; e < 16; e += 2) {
                    c0 += (fabsf(acc[e])     >= COS_TH) ? 1u : 0u;
                    c1 += (fabsf(acc[e + 1]) >= COS_TH) ? 1u : 0u;
                }
            }
            unsigned cnt = c0 + c1;
            cnt += __shfl_down(cnt, 32, 64);   // merge the two row-subhalves
            if (l < 32) {
                int* dst = h ? s_deg1 : s_deg0;
                dst[32 * j + l] = (int)cnt;
            }
        }
    }

    // ---- Phase 4b: boundary rows 192..195 (wave w owns row 192+w).
    // fp32 dots from reconstructed h+l (consistent with split-path values).
    {
        const int r = 192 + w;
        const v8s prv = *(const v8s*)&s_P[r][0];
        const u32 p01 = ((const u32*)&prv)[0];   // shorts 0,1
        const u32 p23 = ((const u32*)&prv)[1];   // shorts 2,3
        const u32 p45 = ((const u32*)&prv)[2];   // shorts 4,5
        const u32 p67 = ((const u32*)&prv)[3];   // shorts 6,7
        const float pe0 = bfhi(p01) + bfhi(p45);
        const float pe1 = bflo(p01) + bflo(p45);
        const float pe2 = bfhi(p23) + bfhi(p67);
        const float pe3 = bflo(p23) + bflo(p67);
        unsigned total = 0u;
        #pragma unroll
        for (int k = 0; k < 4; ++k) {
            int q = 64 * k + l;              // rows >=196 are zero -> miss
            const v8s qrv = *(const v8s*)&s_P[q][0];
            const u32 q01 = ((const u32*)&qrv)[0];
            const u32 q23 = ((const u32*)&qrv)[1];
            const u32 q45 = ((const u32*)&qrv)[2];
            const u32 q67 = ((const u32*)&qrv)[3];
            float d =          pe0 * (bfhi(q01) + bfhi(q45));
            d = fmaf(pe1, bflo(q01) + bflo(q45), d);
            d = fmaf(pe2, bfhi(q23) + bfhi(q67), d);
            d = fmaf(pe3, bflo(q23) + bflo(q67), d);
            bool hit = fabsf(d) >= COS_TH;
            unsigned long long m = __ballot(hit);
            total += (unsigned)__popcll(m);
            if (hit && q < 192)
                atomicAdd(&s_cred[q], 1);    // sparse (~4%)
        }
        if (l == 0)
            s_feats[784 + r] = (float)(int)total - 1.0f;  // self-edge
    }
    __syncthreads();

    // ---- Phase 4c: combine half-counts + boundary credits -> deg features ----
    if (t < 192)
        s_feats[784 + t] = (float)(s_deg0[t] + s_deg1[t] + s_cred[t]) - 1.0f;
    __syncthreads();

    // ---- Phase 5: linear ----
    if (t < 250) {
        int k = t / 25, c = t - 25 * (t / 25);
        const float4* wrow = (const float4*)(lin_w + k * FEAT);
        const float4* fp = (const float4*)s_feats;
        float a0 = 0.0f;
        for (int i = c; i < 245; i += 25) {
            float4 wv = wrow[i];
            float4 f0 = fp[i];
            a0 = fmaf(f0.x, wv.x, a0);
            a0 = fmaf(f0.y, wv.y, a0);
            a0 = fmaf(f0.z, wv.z, a0);
            a0 = fmaf(f0.w, wv.w, a0);
        }
        s_part[t] = a0;
    }
    __syncthreads();

    if (t < 10) {
        float s = lin_b[t];
        #pragma unroll
        for (int i = 0; i < 25; ++i) s += s_part[t * 25 + i];
        s_logits[t] = s;
    }
    __syncthreads();

    // ---- Phase 6: log_softmax ----
    if (t < 10) {
        float m = -INFINITY;
        #pragma unroll
        for (int j2 = 0; j2 < 10; ++j2) m = fmaxf(m, s_logits[j2]);
        float s = 0.0f;
        #pragma unroll
        for (int j2 = 0; j2 < 10; ++j2) s += expf(s_logits[j2] - m);
        out[(size_t)b * 10 + t] = s_logits[t] - m - logf(s);
    }
}

extern "C" void kernel_launch(void* const* d_in, const int* in_sizes, int n_in,
                              void* d_out, int out_size, void* d_ws, size_t ws_size,
                              hipStream_t stream) {
    const float* x      = (const float*)d_in[0];
    const float* conv_w = (const float*)d_in[1];
    const float* conv_b = (const float*)d_in[2];
    const float* lin_w  = (const float*)d_in[3];
    const float* lin_b  = (const float*)d_in[4];
    float* out = (float*)d_out;
    quanv_kernel<<<dim3(8192), dim3(256), 0, stream>>>(x, conv_w, conv_b, lin_w, lin_b, out);
}